// Round 5
// baseline (92.345 us; speedup 1.0000x reference)
//
#include <hip/hip_runtime.h>
#include <hip/hip_bf16.h>
#include <stdint.h>

typedef __bf16 bf16x8 __attribute__((ext_vector_type(8)));
typedef float f32x4 __attribute__((ext_vector_type(4)));

__device__ __forceinline__ uint16_t f32_to_bf16_rne(float f) {
    uint32_t u = __float_as_uint(f);
    u += 0x7fffu + ((u >> 16) & 1u);
    return (uint16_t)(u >> 16);
}

// Convert two fp32 arrays to bf16 (RNE) in one grid-stride kernel.
__global__ void cvt2_kernel(const float* __restrict__ a, long na4,
                            const float* __restrict__ b, long nb4,
                            uint16_t* __restrict__ oa, uint16_t* __restrict__ ob) {
    long i = (long)blockIdx.x * blockDim.x + threadIdx.x;
    const long stride = (long)gridDim.x * blockDim.x;
    const long tot = na4 + nb4;
    for (; i < tot; i += stride) {
        const float4* src; ushort4* dst; long j;
        if (i < na4) { src = (const float4*)a; dst = (ushort4*)oa; j = i; }
        else         { src = (const float4*)b; dst = (ushort4*)ob; j = i - na4; }
        float4 f = src[j];
        ushort4 o;
        o.x = f32_to_bf16_rne(f.x);
        o.y = f32_to_bf16_rne(f.y);
        o.z = f32_to_bf16_rne(f.z);
        o.w = f32_to_bf16_rne(f.w);
        dst[j] = o;
    }
}

// ---------------------------------------------------------------------------
// m201-style sub-phase GEMM: BM=128, BN=256, BK=64, 8 waves (2M x 4N),
// per-wave 64x64. Ring of 3 LDS regions x 48 KiB = 144 KiB.
// Per K64 tile: 2 sub-phases, each
//   { READ8(k-half); STAGE3; [vmcnt(6) in 2nd]; s_barrier; lgkmcnt(0);
//     sched_barrier(0); setprio(1); 16 MFMA; setprio(0); s_barrier }
// Reads are issued BEFORE a barrier and consumed AFTER it (latency hides
// under barrier convergence); counted vmcnt(6) once per K64 keeps 6 loads
// in flight across barriers; 4 barriers per K64 create the wave role-split
// that makes setprio effective (T5 gate).
// XOR swizzle (chunk ^= row&7) on pre-swizzled global src + ds_read offs.
// ---------------------------------------------------------------------------

#define GLD(gp, lp) __builtin_amdgcn_global_load_lds(                           \
    (const __attribute__((address_space(1))) uint32_t*)(gp),                    \
    (__attribute__((address_space(3))) uint32_t*)(void*)(lp), 16, 0, 0)

#define STAGE3a(KOFF, BS) do {                                                  \
    GLD(pA0 + (KOFF), (BS) + t16);                                              \
    GLD(pA1 + (KOFF), (BS) + 8192  + t16);                                      \
    GLD(pB0 + (KOFF), (BS) + 16384 + t16);                                      \
} while (0)

#define STAGE3b(KOFF, BS) do {                                                  \
    GLD(pB1 + (KOFF), (BS) + 24576 + t16);                                      \
    GLD(pB2 + (KOFF), (BS) + 32768 + t16);                                      \
    GLD(pB3 + (KOFF), (BS) + 40960 + t16);                                      \
} while (0)

// Read 4 A-frags + 4 B-frags (one K32 half; SX=0 -> k[0,32), SX=64 -> k[32,64)).
#define READ8(P, BASE, SX) do {                                                 \
    P##a0 = *(const bf16x8*)((BASE) + (aoff0 ^ (SX)));                          \
    P##a1 = *(const bf16x8*)((BASE) + (aoff1 ^ (SX)));                          \
    P##a2 = *(const bf16x8*)((BASE) + (aoff2 ^ (SX)));                          \
    P##a3 = *(const bf16x8*)((BASE) + (aoff3 ^ (SX)));                          \
    P##b0 = *(const bf16x8*)((BASE) + (boff0 ^ (SX)));                          \
    P##b1 = *(const bf16x8*)((BASE) + (boff1 ^ (SX)));                          \
    P##b2 = *(const bf16x8*)((BASE) + (boff2 ^ (SX)));                          \
    P##b3 = *(const bf16x8*)((BASE) + (boff3 ^ (SX)));                          \
} while (0)

#define MFMA16(P) do {                                                          \
    acc[0][0] = __builtin_amdgcn_mfma_f32_16x16x32_bf16(P##a0, P##b0, acc[0][0], 0, 0, 0); \
    acc[0][1] = __builtin_amdgcn_mfma_f32_16x16x32_bf16(P##a0, P##b1, acc[0][1], 0, 0, 0); \
    acc[0][2] = __builtin_amdgcn_mfma_f32_16x16x32_bf16(P##a0, P##b2, acc[0][2], 0, 0, 0); \
    acc[0][3] = __builtin_amdgcn_mfma_f32_16x16x32_bf16(P##a0, P##b3, acc[0][3], 0, 0, 0); \
    acc[1][0] = __builtin_amdgcn_mfma_f32_16x16x32_bf16(P##a1, P##b0, acc[1][0], 0, 0, 0); \
    acc[1][1] = __builtin_amdgcn_mfma_f32_16x16x32_bf16(P##a1, P##b1, acc[1][1], 0, 0, 0); \
    acc[1][2] = __builtin_amdgcn_mfma_f32_16x16x32_bf16(P##a1, P##b2, acc[1][2], 0, 0, 0); \
    acc[1][3] = __builtin_amdgcn_mfma_f32_16x16x32_bf16(P##a1, P##b3, acc[1][3], 0, 0, 0); \
    acc[2][0] = __builtin_amdgcn_mfma_f32_16x16x32_bf16(P##a2, P##b0, acc[2][0], 0, 0, 0); \
    acc[2][1] = __builtin_amdgcn_mfma_f32_16x16x32_bf16(P##a2, P##b1, acc[2][1], 0, 0, 0); \
    acc[2][2] = __builtin_amdgcn_mfma_f32_16x16x32_bf16(P##a2, P##b2, acc[2][2], 0, 0, 0); \
    acc[2][3] = __builtin_amdgcn_mfma_f32_16x16x32_bf16(P##a2, P##b3, acc[2][3], 0, 0, 0); \
    acc[3][0] = __builtin_amdgcn_mfma_f32_16x16x32_bf16(P##a3, P##b0, acc[3][0], 0, 0, 0); \
    acc[3][1] = __builtin_amdgcn_mfma_f32_16x16x32_bf16(P##a3, P##b1, acc[3][1], 0, 0, 0); \
    acc[3][2] = __builtin_amdgcn_mfma_f32_16x16x32_bf16(P##a3, P##b2, acc[3][2], 0, 0, 0); \
    acc[3][3] = __builtin_amdgcn_mfma_f32_16x16x32_bf16(P##a3, P##b3, acc[3][3], 0, 0, 0); \
} while (0)

#define ROT3() do { uint8_t* t_ = r0; r0 = r1; r1 = r2; r2 = t_; } while (0)

// One sub-phase: reads + staging pre-barrier; MFMA cluster post-barrier.
#define SUBPHASE(SET, SX, STG, VM) do {                                         \
    READ8(SET, r0, SX);                                                         \
    STG;                                                                        \
    VM;                                                                         \
    __builtin_amdgcn_s_barrier();                                               \
    asm volatile("s_waitcnt lgkmcnt(0)" ::: "memory");                          \
    __builtin_amdgcn_sched_barrier(0);                                          \
    __builtin_amdgcn_s_setprio(1); MFMA16(SET); __builtin_amdgcn_s_setprio(0);  \
    __builtin_amdgcn_s_barrier();                                               \
    __builtin_amdgcn_sched_barrier(0);                                          \
} while (0)

__global__ __launch_bounds__(512, 2) void gemm_sp_bf16(
    const uint16_t* __restrict__ A,   // M x K bf16 (x)
    const uint16_t* __restrict__ B,   // N x K bf16 (weight)
    const float* __restrict__ bias,
    float* __restrict__ C, int M, int N, int K)
{
    extern __shared__ __align__(16) uint8_t lds[];
    const int tid  = threadIdx.x;
    const int lane = tid & 63;
    const int wave = tid >> 6;
    const int wr = wave >> 2;   // 0..1 (M)
    const int wc = wave & 3;    // 0..3 (N)

    // Bijective XCD-aware swizzle.
    const int nwg = gridDim.x;
    int swz;
    {
        const int q = nwg >> 3, r = nwg & 7;
        const int xcd = blockIdx.x & 7, k = blockIdx.x >> 3;
        swz = (xcd < r ? xcd * (q + 1) : r * (q + 1) + (xcd - r) * q) + k;
    }
    const int MB = M >> 7;
    const int brow = swz % MB;
    const int bcol = swz / MB;

    // Staging addressing (pre-swizzled global source, linear LDS dest).
    const int t16  = tid * 16;
    const int trow = tid >> 3;                       // 0..63
    const int kc   = (tid & 7) ^ (trow & 7);         // swizzled 16B-chunk index
    const uint16_t* pA0 = A + (size_t)(brow * 128 + trow) * K + kc * 8;
    const uint16_t* pA1 = pA0 + (size_t)64 * K;
    const uint16_t* pB0 = B + (size_t)(bcol * 256 + trow) * K + kc * 8;
    const uint16_t* pB1 = pB0 + (size_t)64 * K;
    const uint16_t* pB2 = pB0 + (size_t)128 * K;
    const uint16_t* pB3 = pB0 + (size_t)192 * K;

    // Fragment read offsets (region-relative), swizzled.
    const int lm   = lane & 15;
    const int g    = lane >> 4;
    const int slot = (g ^ (lm & 7)) * 16;
    const int aoff0 = (wr * 64 +  0 + lm) * 128 + slot;
    const int aoff1 = (wr * 64 + 16 + lm) * 128 + slot;
    const int aoff2 = (wr * 64 + 32 + lm) * 128 + slot;
    const int aoff3 = (wr * 64 + 48 + lm) * 128 + slot;
    const int boff0 = 16384 + (wc * 64 +  0 + lm) * 128 + slot;
    const int boff1 = 16384 + (wc * 64 + 16 + lm) * 128 + slot;
    const int boff2 = 16384 + (wc * 64 + 32 + lm) * 128 + slot;
    const int boff3 = 16384 + (wc * 64 + 48 + lm) * 128 + slot;

    f32x4 acc[4][4];
#pragma unroll
    for (int m = 0; m < 4; ++m)
#pragma unroll
        for (int n = 0; n < 4; ++n)
            acc[m][n] = (f32x4){0.f, 0.f, 0.f, 0.f};

    // Fragment register sets (x = k[0,32), y = k[32,64) of current region).
    bf16x8 xa0, xa1, xa2, xa3, xb0, xb1, xb2, xb3;
    bf16x8 ya0, ya1, ya2, ya3, yb0, yb1, yb2, yb3;

    const int nt = K >> 6;   // K64 tiles; launcher guarantees >= 4
    uint8_t* r0 = lds;
    uint8_t* r1 = lds + 49152;
    uint8_t* r2 = lds + 98304;
    size_t kk = 128;         // k-offset staged by the current phase (region p+2)

    // Prologue: stage regions 0,1; publish region 0.
    STAGE3a(0, r0); STAGE3b(0, r0);
    STAGE3a(64, r1); STAGE3b(64, r1);
    asm volatile("s_waitcnt vmcnt(6)" ::: "memory");
    __builtin_amdgcn_s_barrier();
    __builtin_amdgcn_sched_barrier(0);

    // Main loop: phases 0 .. nt-3 (each stages region p+2).
    for (int p = 0; p <= nt - 3; ++p) {
        SUBPHASE(x, 0,  STAGE3a(kk, r2), (void)0);
        SUBPHASE(y, 64, STAGE3b(kk, r2),
                 asm volatile("s_waitcnt vmcnt(6)" ::: "memory"));
        ROT3(); kk += 64;
    }
    // Phase nt-2: no staging; drain everything (publishes region nt-1).
    SUBPHASE(x, 0,  (void)0, (void)0);
    SUBPHASE(y, 64, (void)0, asm volatile("s_waitcnt vmcnt(0)" ::: "memory"));
    ROT3();
    // Phase nt-1: final region.
    SUBPHASE(x, 0,  (void)0, (void)0);
    SUBPHASE(y, 64, (void)0, (void)0);

    // Epilogue: D mapping col = lane&15 (N), row = (lane>>4)*4 + t (M).
    const int crow0 = brow * 128 + wr * 64 + (lane >> 4) * 4;
    const int ccol0 = bcol * 256 + wc * 64 + lm;
#pragma unroll
    for (int nf = 0; nf < 4; ++nf) {
        const int col = ccol0 + nf * 16;
        const float bv = bias[col];
#pragma unroll
        for (int mf = 0; mf < 4; ++mf) {
#pragma unroll
            for (int tt = 0; tt < 4; ++tt) {
                const int row = crow0 + mf * 16 + tt;
                C[(size_t)row * N + col] = acc[mf][nf][tt] + bv;
            }
        }
    }
}

// ---------------------------------------------------------------------------
// Fallback 1: verified m97-structure 128x128 kernel.
// ---------------------------------------------------------------------------
__global__ __launch_bounds__(256) void gemm_bf16_kernel(
    const uint16_t* __restrict__ A,
    const uint16_t* __restrict__ B,
    const float* __restrict__ bias,
    float* __restrict__ C, int M, int N, int K)
{
    __shared__ __align__(16) uint16_t Alds[128 * 32];
    __shared__ __align__(16) uint16_t Blds[128 * 32];

    const int tid  = threadIdx.x;
    const int lane = tid & 63;
    const int wave = tid >> 6;
    const int wm = wave >> 1, wn = wave & 1;

    const int MB = M >> 7;
    const int brow = blockIdx.x % MB;
    const int bcol = blockIdx.x / MB;

    const int off0 = wave * 1024 + lane * 16;
    const int row0 = off0 >> 6;
    const int colb = off0 & 63;

    const uint8_t* gA0 = (const uint8_t*)A + ((size_t)(brow * 128 + row0) * K) * 2 + colb;
    const uint8_t* gA1 = gA0 + (size_t)64 * K * 2;
    const uint8_t* gB0 = (const uint8_t*)B + ((size_t)(bcol * 128 + row0) * K) * 2 + colb;
    const uint8_t* gB1 = gB0 + (size_t)64 * K * 2;

    uint32_t* lA0 = (uint32_t*)((uint8_t*)Alds + off0);
    uint32_t* lA1 = (uint32_t*)((uint8_t*)Alds + off0 + 4096);
    uint32_t* lB0 = (uint32_t*)((uint8_t*)Blds + off0);
    uint32_t* lB1 = (uint32_t*)((uint8_t*)Blds + off0 + 4096);

#define STAGE_OLD() do {                                                                   \
    __builtin_amdgcn_global_load_lds((const __attribute__((address_space(1))) uint32_t*)gA0, \
                                     (__attribute__((address_space(3))) uint32_t*)lA0, 16, 0, 0); \
    __builtin_amdgcn_global_load_lds((const __attribute__((address_space(1))) uint32_t*)gA1, \
                                     (__attribute__((address_space(3))) uint32_t*)lA1, 16, 0, 0); \
    __builtin_amdgcn_global_load_lds((const __attribute__((address_space(1))) uint32_t*)gB0, \
                                     (__attribute__((address_space(3))) uint32_t*)lB0, 16, 0, 0); \
    __builtin_amdgcn_global_load_lds((const __attribute__((address_space(1))) uint32_t*)gB1, \
                                     (__attribute__((address_space(3))) uint32_t*)lB1, 16, 0, 0); \
    gA0 += 64; gA1 += 64; gB0 += 64; gB1 += 64;                                            \
} while (0)

    f32x4 acc[4][4];
#pragma unroll
    for (int mf = 0; mf < 4; ++mf)
#pragma unroll
        for (int nf = 0; nf < 4; ++nf)
            acc[mf][nf] = (f32x4){0.f, 0.f, 0.f, 0.f};

    const int nk = K >> 5;
    STAGE_OLD();

    const int arow = wm * 64 + (lane & 15);
    const int brw  = wn * 64 + (lane & 15);
    const int ke   = (lane >> 4) * 8;

    for (int kt = 0; kt < nk; ++kt) {
        __syncthreads();
        bf16x8 af[4], bfr[4];
#pragma unroll
        for (int mf = 0; mf < 4; ++mf)
            af[mf] = *(const bf16x8*)(&Alds[(arow + mf * 16) * 32 + ke]);
#pragma unroll
        for (int nf = 0; nf < 4; ++nf)
            bfr[nf] = *(const bf16x8*)(&Blds[(brw + nf * 16) * 32 + ke]);
        __syncthreads();
        if (kt + 1 < nk) STAGE_OLD();
#pragma unroll
        for (int mf = 0; mf < 4; ++mf)
#pragma unroll
            for (int nf = 0; nf < 4; ++nf)
                acc[mf][nf] = __builtin_amdgcn_mfma_f32_16x16x32_bf16(
                    af[mf], bfr[nf], acc[mf][nf], 0, 0, 0);
    }
#undef STAGE_OLD

    const int crow0 = brow * 128 + wm * 64 + (lane >> 4) * 4;
    const int ccol0 = bcol * 128 + wn * 64 + (lane & 15);
#pragma unroll
    for (int nf = 0; nf < 4; ++nf) {
        const int col = ccol0 + nf * 16;
        const float bv = bias[col];
#pragma unroll
        for (int mf = 0; mf < 4; ++mf) {
#pragma unroll
            for (int t = 0; t < 4; ++t) {
                const int row = crow0 + mf * 16 + t;
                C[(size_t)row * N + col] = acc[mf][nf][t] + bv;
            }
        }
    }
}

// Fallback 2: fp32 vector GEMM, one block per row.
__global__ void gemm_fallback(const float* __restrict__ x, const float* __restrict__ w,
                              const float* __restrict__ bias, float* __restrict__ out,
                              int M, int N, int K) {
    extern __shared__ float xs[];
    const int b = blockIdx.x;
    for (int k = threadIdx.x; k < K; k += blockDim.x) xs[k] = x[(size_t)b * K + k];
    __syncthreads();
    for (int j = threadIdx.x; j < N; j += blockDim.x) {
        const float* wr = w + (size_t)j * K;
        float s = 0.f;
        for (int k = 0; k < K; ++k) s += xs[k] * wr[k];
        out[(size_t)b * N + j] = s + bias[j];
    }
}

extern "C" void kernel_launch(void* const* d_in, const int* in_sizes, int n_in,
                              void* d_out, int out_size, void* d_ws, size_t ws_size,
                              hipStream_t stream) {
    const float* x    = (const float*)d_in[0];
    const float* w    = (const float*)d_in[1];
    const float* bias = (const float*)d_in[2];
    float* out = (float*)d_out;

    const int N = in_sizes[2];
    const int K = in_sizes[1] / N;
    const int M = in_sizes[0] / K;

    const size_t need = ((size_t)M * K + (size_t)N * K) * 2;
    const bool ws_ok = ws_size >= need;

    if ((M % 128 == 0) && (N % 256 == 0) && (K % 128 == 0) && (K >= 256) && ws_ok) {
        uint16_t* xb = (uint16_t*)d_ws;
        uint16_t* wb = xb + (size_t)M * K;
        const long na4 = (long)M * K / 4, nb4 = (long)N * K / 4;
        cvt2_kernel<<<2048, 256, 0, stream>>>(x, na4, w, nb4, xb, wb);
        (void)hipFuncSetAttribute((const void*)gemm_sp_bf16,
                                  hipFuncAttributeMaxDynamicSharedMemorySize, 147456);
        dim3 grid((M / 128) * (N / 256));
        gemm_sp_bf16<<<grid, 512, 147456, stream>>>(xb, wb, bias, out, M, N, K);
    } else if ((M % 128 == 0) && (N % 128 == 0) && (K % 32 == 0) && ws_ok) {
        uint16_t* xb = (uint16_t*)d_ws;
        uint16_t* wb = xb + (size_t)M * K;
        const long na4 = (long)M * K / 4, nb4 = (long)N * K / 4;
        cvt2_kernel<<<2048, 256, 0, stream>>>(x, na4, w, nb4, xb, wb);
        dim3 grid((M / 128) * (N / 128));
        gemm_bf16_kernel<<<grid, 256, 0, stream>>>(xb, wb, bias, out, M, N, K);
    } else {
        gemm_fallback<<<M, 256, (size_t)K * 4, stream>>>(x, w, bias, out, M, N, K);
    }
}